// Round 1
// 2099.589 us; speedup vs baseline: 1.0621x; 1.0621x over previous
//
#include <hip/hip_runtime.h>
#include <hip/hip_bf16.h>
#include <math.h>

#define B_    16
#define T_    256
#define D_    1024
#define H_    16
#define DH_   64
#define NB_   6
#define GD_   300
#define GDP_  320
#define MLPH_ 2048
#define FFH_  4096
#define NTOK  (B_ * T_)
#define NEGV  -4294967296.0f

typedef __hip_bfloat16 bf16;
typedef __attribute__((ext_vector_type(8))) short short8;
typedef __attribute__((ext_vector_type(4))) float floatx4;

__device__ __forceinline__ unsigned short f2b(float v) {
    __hip_bfloat16 h = __float2bfloat16(v);
    return __builtin_bit_cast(unsigned short, h);
}
__device__ __forceinline__ float b2f(unsigned short u) {
    union { unsigned i; float f; } x; x.i = ((unsigned)u) << 16; return x.f;
}

// async 16B global -> LDS
__device__ __forceinline__ void gld16(const void* g, void* l) {
    __builtin_amdgcn_global_load_lds(
        (const __attribute__((address_space(1))) unsigned int*)g,
        (__attribute__((address_space(3))) unsigned int*)(uintptr_t)l,
        16, 0, 0);
}

// ---------------------------------------------------------------------------
// fp32 -> bf16 transpose: W (K x N) -> WT (N x Kpad). k >= K zero-filled.
// ---------------------------------------------------------------------------
__global__ __launch_bounds__(256)
void convT_kernel(const float* __restrict__ W, bf16* __restrict__ WT,
                  int K, int N, int Kpad, size_t strideIn, size_t strideOut)
{
    __shared__ float t[32][33];
    const float* Wb = W + (size_t)blockIdx.z * strideIn;
    bf16* WTb = WT + (size_t)blockIdx.z * strideOut;
    int n0 = blockIdx.x * 32, k0 = blockIdx.y * 32;
    int tx = threadIdx.x & 31, ty = threadIdx.x >> 5;
#pragma unroll
    for (int r = 0; r < 4; r++) {
        int k = k0 + ty + r * 8;
        t[ty + r * 8][tx] = (k < K) ? Wb[(size_t)k * N + n0 + tx] : 0.f;
    }
    __syncthreads();
#pragma unroll
    for (int r = 0; r < 4; r++) {
        int n = n0 + ty + r * 8;
        WTb[(size_t)n * Kpad + k0 + tx] = __float2bfloat16(t[tx][ty + r * 8]);
    }
}

// ---------------------------------------------------------------------------
// Embedding gather -> bf16, padded 300->320
// ---------------------------------------------------------------------------
__global__ __launch_bounds__(256)
void gather_kernel(const int* __restrict__ ipt, const float* __restrict__ emb,
                   bf16* __restrict__ out)
{
    int row = blockIdx.x;
    int v = ipt[row];
    const float* src = emb + (size_t)v * GD_;
    bf16* dst = out + (size_t)row * GDP_;
    for (int c = threadIdx.x; c < GDP_; c += blockDim.x)
        dst[c] = (c < GD_) ? __float2bfloat16(src[c]) : __float2bfloat16(0.f);
}

// ---------------------------------------------------------------------------
// graph/key-mask -> additive bias (0 or NEGV), bf16. grid = B*T blocks.
// ---------------------------------------------------------------------------
__global__ __launch_bounds__(256)
void gbias_kernel(const int* __restrict__ mask, const int* __restrict__ graph,
                  bf16* __restrict__ gb)
{
    int r = blockIdx.x;              // b*T + q
    int b = r >> 8;
    int k = threadIdx.x;
    int ok = mask[b * T_ + k] & graph[(size_t)r * T_ + k];
    gb[(size_t)r * T_ + k] = __float2bfloat16(ok ? 0.f : NEGV);
}

// concat per-layer q/k/v biases -> (NB, 3072)
__global__ __launch_bounds__(256)
void bcat_kernel(const float* __restrict__ bq, const float* __restrict__ bk,
                 const float* __restrict__ bv, float* __restrict__ out)
{
    int i = blockIdx.x;
    int j = blockIdx.y * 256 + threadIdx.x;   // 0..3071
    float v = (j < 1024) ? bq[i * 1024 + j]
            : (j < 2048) ? bk[i * 1024 + j - 1024]
                         : bv[i * 1024 + j - 2048];
    out[i * 3072 + j] = v;
}

// ---------------------------------------------------------------------------
// bf16 MFMA GEMM (m97 structure): 128x128 tile, BK=64, 4 waves.
// QKVQ: multiply cols < 1024 by 0.125 (fold attention scale into Q).
// PARTIAL: split-K mode - blockIdx.z selects K-slice of length K (lda = full
//          row stride); raw fp32 partial written to C + z*M*N, no epilogue.
// ---------------------------------------------------------------------------
template<bool RELU, bool ADDPOS, bool DUAL, bool QKVQ, bool PARTIAL, typename OutT>
__global__ __launch_bounds__(256)
void mm_bf16(const bf16* __restrict__ A, const bf16* __restrict__ BT,
             const float* __restrict__ bias, const float* __restrict__ pos,
             OutT* __restrict__ C, bf16* __restrict__ C2,
             int M, int N, int K, int lda)
{
    __shared__ __align__(16) short lsA[8192];
    __shared__ __align__(16) short lsB[8192];
    const int tid = threadIdx.x;
    const int wv = tid >> 6, ln = tid & 63;
    const int m0 = blockIdx.y * 128, n0 = blockIdx.x * 128;
    const int wm = (wv >> 1) * 64, wn = (wv & 1) * 64;
    const int ml = ln & 15, q = ln >> 4;
    const int koff = PARTIAL ? blockIdx.z * K : 0;

    floatx4 acc[4][4] = {};

    const int cbase[4] = { (0 * 4 + wv) * 64, (1 * 4 + wv) * 64, (2 * 4 + wv) * 64, (3 * 4 + wv) * 64 };
    int srow[4], skc[4];
#pragma unroll
    for (int p = 0; p < 4; p++) {
        int c = cbase[p] + ln;
        srow[p] = c >> 3;
        skc[p] = (c & 7) ^ (srow[p] & 7);
    }

    for (int kt = koff; kt < koff + K; kt += 64) {
#pragma unroll
        for (int p = 0; p < 4; p++) {
            const bf16* ga = A + (size_t)(m0 + srow[p]) * lda + kt + skc[p] * 8;
            const bf16* gb = BT + (size_t)(n0 + srow[p]) * lda + kt + skc[p] * 8;
            gld16(ga, &lsA[cbase[p] * 8]);
            gld16(gb, &lsB[cbase[p] * 8]);
        }
        __syncthreads();

        short8 af[4][2], bfr[4][2];
#pragma unroll
        for (int i = 0; i < 4; i++) {
#pragma unroll
            for (int ks = 0; ks < 2; ks++) {
                int r = wm + i * 16 + ml;
                int kc = ks * 4 + q;
                af[i][ks] = *(const short8*)&lsA[(r * 8 + (kc ^ (r & 7))) * 8];
                int n = wn + i * 16 + ml;
                bfr[i][ks] = *(const short8*)&lsB[(n * 8 + (kc ^ (n & 7))) * 8];
            }
        }
#pragma unroll
        for (int ks = 0; ks < 2; ks++)
#pragma unroll
            for (int i = 0; i < 4; i++)
#pragma unroll
                for (int j = 0; j < 4; j++)
                    acc[i][j] = __builtin_amdgcn_mfma_f32_16x16x32_bf16(
                        af[i][ks], bfr[j][ks], acc[i][j], 0, 0, 0);
        __syncthreads();
    }

#pragma unroll
    for (int i = 0; i < 4; i++) {
#pragma unroll
        for (int j = 0; j < 4; j++) {
            int col = n0 + wn + j * 16 + ml;
            float bb = PARTIAL ? 0.f : bias[col];
            float sc = (QKVQ && col < D_) ? 0.125f : 1.0f;
#pragma unroll
            for (int rg = 0; rg < 4; rg++) {
                int row = m0 + wm + i * 16 + q * 4 + rg;
                float v = acc[i][j][rg];
                size_t idx = (size_t)row * N + col;
                if constexpr (PARTIAL) {
                    C[(size_t)blockIdx.z * M * N + idx] = v;
                } else {
                    v += bb;
                    if (ADDPOS) v += pos[(size_t)(row & (T_ - 1)) * N + col];
                    if (RELU) v = fmaxf(v, 0.f);
                    if (QKVQ) v *= sc;
                    if constexpr (sizeof(OutT) == 4) C[idx] = v;
                    else C[idx] = (OutT)__float2bfloat16(v);
                    if (DUAL) C2[idx] = __float2bfloat16(v);
                }
            }
        }
    }
}

// ---------------------------------------------------------------------------
// MFMA attention. Block = (b, h, 64-query chunk); 4 waves x 16 q-rows.
// QKV: (NTOK, 3072) bf16, Q pre-scaled by 1/8. gbias: (B*T, T) bf16 additive.
// S strip (16x256) in registers; softmax via 16-lane shuffles; P through
// LDS (XOR-swizzled); V^T staged in LDS. Output fp32.
// ---------------------------------------------------------------------------
__global__ __launch_bounds__(256, 2)
void attn2_kernel(const bf16* __restrict__ QKV, const bf16* __restrict__ gbias,
                  const int* __restrict__ mask, float* __restrict__ O)
{
    __shared__ unsigned short lds[32768];       // [0,16384): V^T; [16384,32768): P
    const int tid = threadIdx.x;
    const int wv = tid >> 6, ln = tid & 63;
    const int ml = ln & 15, qq = ln >> 4;
    const int qc = blockIdx.x & 3;
    const int h  = (blockIdx.x >> 2) & 15;
    const int b  = blockIdx.x >> 6;
    const int tok0 = b * T_;

    const unsigned short* QKVu = (const unsigned short*)QKV;

    // ---- stage V^T (64 x 256, swizzled 16B chunks) ----
#pragma unroll
    for (int it = 0; it < 4; it++) {
        int k = (tid >> 2) + it * 64;
        int d0 = (tid & 3) * 16;
        const unsigned short* src = QKVu + (size_t)(tok0 + k) * 3072 + 2048 + h * 64 + d0;
        union { uint4 u[2]; unsigned short s[16]; } v;
        v.u[0] = *(const uint4*)src;
        v.u[1] = *(const uint4*)(src + 8);
#pragma unroll
        for (int e = 0; e < 16; e++) {
            int d = d0 + e;
            lds[d * 256 + (((k >> 3) ^ (d & 7)) << 3) + (k & 7)] = v.s[e];
        }
    }

    // ---- Q fragments (reused across all key tiles) ----
    const int q0 = qc * 64 + wv * 16;
    short8 qa[2];
#pragma unroll
    for (int ks = 0; ks < 2; ks++)
        qa[ks] = *(const short8*)(QKVu + (size_t)(tok0 + q0 + ml) * 3072 + h * 64 + ks * 32 + qq * 8);

    __syncthreads();

    // ---- S = Q K^T (16 j-tiles of 16 keys), K frags direct from global ----
    floatx4 sb[16] = {};
#pragma unroll
    for (int jt = 0; jt < 16; jt++) {
        const unsigned short* kr = QKVu + (size_t)(tok0 + jt * 16 + ml) * 3072 + 1024 + h * 64 + qq * 8;
        short8 kb0 = *(const short8*)kr;
        short8 kb1 = *(const short8*)(kr + 32);
        sb[jt] = __builtin_amdgcn_mfma_f32_16x16x32_bf16(qa[0], kb0, sb[jt], 0, 0, 0);
        sb[jt] = __builtin_amdgcn_mfma_f32_16x16x32_bf16(qa[1], kb1, sb[jt], 0, 0, 0);
    }

    // ---- add mask/graph bias ----
    const unsigned short* gb = (const unsigned short*)gbias + (size_t)(tok0 + q0) * T_;
#pragma unroll
    for (int jt = 0; jt < 16; jt++)
#pragma unroll
        for (int r = 0; r < 4; r++)
            sb[jt][r] += b2f(gb[(size_t)(qq * 4 + r) * T_ + jt * 16 + ml]);

    // ---- softmax (rows q0 + qq*4 + r) ----
    float mx[4];
#pragma unroll
    for (int r = 0; r < 4; r++) {
        float m = sb[0][r];
#pragma unroll
        for (int jt = 1; jt < 16; jt++) m = fmaxf(m, sb[jt][r]);
#pragma unroll
        for (int off = 1; off < 16; off <<= 1) m = fmaxf(m, __shfl_xor(m, off, 64));
        mx[r] = m;
    }
    float lsum[4] = {0.f, 0.f, 0.f, 0.f};
    unsigned short* Pw = lds + 16384 + wv * 4096;
#pragma unroll
    for (int jt = 0; jt < 16; jt++) {
#pragma unroll
        for (int r = 0; r < 4; r++) {
            float e = __expf(sb[jt][r] - mx[r]);
            lsum[r] += e;
            int row = qq * 4 + r;
            int k = jt * 16 + ml;
            Pw[row * 256 + (((k >> 3) ^ (row & 7)) << 3) + (k & 7)] = f2b(e);
        }
    }
#pragma unroll
    for (int r = 0; r < 4; r++)
#pragma unroll
        for (int off = 1; off < 16; off <<= 1) lsum[r] += __shfl_xor(lsum[r], off, 64);

    __syncthreads();

    // ---- O = P V (contraction over 256 keys, 8 MFMA steps) ----
    floatx4 oa[4] = {};
    const unsigned short* Pr = lds + 16384 + wv * 4096;
#pragma unroll
    for (int ks = 0; ks < 8; ks++) {
        short8 pa = *(const short8*)&Pr[ml * 256 + (((ks * 4 + qq) ^ (ml & 7)) << 3)];
#pragma unroll
        for (int jd = 0; jd < 4; jd++) {
            int n = jd * 16 + ml;
            short8 vb = *(const short8*)&lds[n * 256 + (((ks * 4 + qq) ^ (n & 7)) << 3)];
            oa[jd] = __builtin_amdgcn_mfma_f32_16x16x32_bf16(pa, vb, oa[jd], 0, 0, 0);
        }
    }

    // ---- epilogue: scale by 1/l and query mask ----
    float fin[4];
#pragma unroll
    for (int r = 0; r < 4; r++) {
        int row = q0 + qq * 4 + r;
        fin[r] = (float)mask[tok0 + row] / lsum[r];
    }
#pragma unroll
    for (int jd = 0; jd < 4; jd++)
#pragma unroll
        for (int r = 0; r < 4; r++) {
            int row = q0 + qq * 4 + r;
            O[(size_t)(tok0 + row) * D_ + h * 64 + jd * 16 + ml] = oa[jd][r] * fin[r];
        }
}

// ---------------------------------------------------------------------------
// Residual add + LayerNorm (fp32) + bf16 copy
// ---------------------------------------------------------------------------
__global__ __launch_bounds__(256)
void add_ln_kernel(const float* __restrict__ Xin, const float* __restrict__ Yin,
                   const float* __restrict__ g, const float* __restrict__ beta,
                   float* __restrict__ Out, bf16* __restrict__ Outb)
{
    const int row = blockIdx.x;
    const int tid = threadIdx.x;
    const float4 a = ((const float4*)(Xin + (size_t)row * D_))[tid];
    const float4 b = ((const float4*)(Yin + (size_t)row * D_))[tid];
    float v0 = a.x + b.x, v1 = a.y + b.y, v2 = a.z + b.z, v3 = a.w + b.w;

    __shared__ float red[8];
    float lsum = v0 + v1 + v2 + v3;
#pragma unroll
    for (int off = 32; off > 0; off >>= 1) lsum += __shfl_xor(lsum, off, 64);
    int wave = tid >> 6;
    if ((tid & 63) == 0) red[wave] = lsum;
    __syncthreads();
    float mean = (red[0] + red[1] + red[2] + red[3]) * (1.f / (float)D_);

    float d0 = v0 - mean, d1 = v1 - mean, d2 = v2 - mean, d3 = v3 - mean;
    float ls2 = d0 * d0 + d1 * d1 + d2 * d2 + d3 * d3;
#pragma unroll
    for (int off = 32; off > 0; off >>= 1) ls2 += __shfl_xor(ls2, off, 64);
    if ((tid & 63) == 0) red[4 + wave] = ls2;
    __syncthreads();
    float var = (red[4] + red[5] + red[6] + red[7]) * (1.f / (float)D_);
    float inv = 1.f / sqrtf(var + 1e-8f);

    int col = tid * 4;
    float4 gv = *(const float4*)(g + col);
    float4 bv = *(const float4*)(beta + col);
    float4 o;
    o.x = d0 * inv * gv.x + bv.x;
    o.y = d1 * inv * gv.y + bv.y;
    o.z = d2 * inv * gv.z + bv.z;
    o.w = d3 * inv * gv.w + bv.w;
    ((float4*)(Out + (size_t)row * D_))[tid] = o;

    union { unsigned short u[4]; uint2 v; } pk;
    pk.u[0] = f2b(o.x); pk.u[1] = f2b(o.y); pk.u[2] = f2b(o.z); pk.u[3] = f2b(o.w);
    *(uint2*)&Outb[(size_t)row * D_ + col] = pk.v;
}

// ---------------------------------------------------------------------------
// Split-K reduce (NP partials) + bias + residual add + LayerNorm + bf16 copy
// ---------------------------------------------------------------------------
template<int NP>
__global__ __launch_bounds__(256)
void add_ln_red_kernel(const float* __restrict__ Xin, const float* __restrict__ P,
                       const float* __restrict__ bias,
                       const float* __restrict__ g, const float* __restrict__ beta,
                       float* __restrict__ Out, bf16* __restrict__ Outb)
{
    const int row = blockIdx.x;
    const int tid = threadIdx.x;
    const int col = tid * 4;
    const float4 a = ((const float4*)(Xin + (size_t)row * D_))[tid];
    const float4 bs = *(const float4*)(bias + col);
    float v0 = a.x + bs.x, v1 = a.y + bs.y, v2 = a.z + bs.z, v3 = a.w + bs.w;
#pragma unroll
    for (int s = 0; s < NP; s++) {
        const float4 pp = ((const float4*)(P + (size_t)s * NTOK * D_ + (size_t)row * D_))[tid];
        v0 += pp.x; v1 += pp.y; v2 += pp.z; v3 += pp.w;
    }

    __shared__ float red[8];
    float lsum = v0 + v1 + v2 + v3;
#pragma unroll
    for (int off = 32; off > 0; off >>= 1) lsum += __shfl_xor(lsum, off, 64);
    int wave = tid >> 6;
    if ((tid & 63) == 0) red[wave] = lsum;
    __syncthreads();
    float mean = (red[0] + red[1] + red[2] + red[3]) * (1.f / (float)D_);

    float d0 = v0 - mean, d1 = v1 - mean, d2 = v2 - mean, d3 = v3 - mean;
    float ls2 = d0 * d0 + d1 * d1 + d2 * d2 + d3 * d3;
#pragma unroll
    for (int off = 32; off > 0; off >>= 1) ls2 += __shfl_xor(ls2, off, 64);
    if ((tid & 63) == 0) red[4 + wave] = ls2;
    __syncthreads();
    float var = (red[4] + red[5] + red[6] + red[7]) * (1.f / (float)D_);
    float inv = 1.f / sqrtf(var + 1e-8f);

    float4 gv = *(const float4*)(g + col);
    float4 bv = *(const float4*)(beta + col);
    float4 o;
    o.x = d0 * inv * gv.x + bv.x;
    o.y = d1 * inv * gv.y + bv.y;
    o.z = d2 * inv * gv.z + bv.z;
    o.w = d3 * inv * gv.w + bv.w;
    ((float4*)(Out + (size_t)row * D_))[tid] = o;

    union { unsigned short u[4]; uint2 v; } pk;
    pk.u[0] = f2b(o.x); pk.u[1] = f2b(o.y); pk.u[2] = f2b(o.z); pk.u[3] = f2b(o.w);
    *(uint2*)&Outb[(size_t)row * D_ + col] = pk.v;
}

// ---------------------------------------------------------------------------
// Split-K reduce for MLP2: sum NP partials + bias + positional, write fp32+bf16
// ---------------------------------------------------------------------------
template<int NP>
__global__ __launch_bounds__(256)
void mlp_fin_kernel(const float* __restrict__ P, const float* __restrict__ bias,
                    const float* __restrict__ pos, float* __restrict__ X,
                    bf16* __restrict__ Xb)
{
    const int row = blockIdx.x;
    const int tid = threadIdx.x;
    const int col = tid * 4;
    float4 v = *(const float4*)(bias + col);
    const float4 pv = *(const float4*)(pos + (size_t)(row & (T_ - 1)) * D_ + col);
    v.x += pv.x; v.y += pv.y; v.z += pv.z; v.w += pv.w;
#pragma unroll
    for (int s = 0; s < NP; s++) {
        const float4 p = ((const float4*)(P + (size_t)s * NTOK * D_ + (size_t)row * D_))[tid];
        v.x += p.x; v.y += p.y; v.z += p.z; v.w += p.w;
    }
    ((float4*)(X + (size_t)row * D_))[tid] = v;
    union { unsigned short u[4]; uint2 q; } pk;
    pk.u[0] = f2b(v.x); pk.u[1] = f2b(v.y); pk.u[2] = f2b(v.z); pk.u[3] = f2b(v.w);
    *(uint2*)&Xb[(size_t)row * D_ + col] = pk.q;
}

// ---------------------------------------------------------------------------
extern "C" void kernel_launch(void* const* d_in, const int* in_sizes, int n_in,
                              void* d_out, int out_size, void* d_ws, size_t ws_size,
                              hipStream_t stream)
{
    const int*   syb_ipt   = (const int*)d_in[0];
    const int*   syb_mask  = (const int*)d_in[1];
    const int*   syb_graph = (const int*)d_in[2];
    const float* emb       = (const float*)d_in[3];
    const float* mlp_w1    = (const float*)d_in[4];
    const float* mlp_b1    = (const float*)d_in[5];
    const float* mlp_w2    = (const float*)d_in[6];
    const float* mlp_b2    = (const float*)d_in[7];
    const float* pos       = (const float*)d_in[8];
    const float* wq        = (const float*)d_in[9];
    const float* bq        = (const float*)d_in[10];
    const float* wk        = (const float*)d_in[11];
    const float* bk        = (const float*)d_in[12];
    const float* wv        = (const float*)d_in[13];
    const float* bv        = (const float*)d_in[14];
    const float* ln1g      = (const float*)d_in[15];
    const float* ln1b      = (const float*)d_in[16];
    const float* ffw1      = (const float*)d_in[17];
    const float* ffb1      = (const float*)d_in[18];
    const float* ffw2      = (const float*)d_in[19];
    const float* ffb2      = (const float*)d_in[20];
    const float* ln2g      = (const float*)d_in[21];
    const float* ln2b      = (const float*)d_in[22];

    char* p = (char*)d_ws;
    auto alloc = [&](size_t bytes) { char* r = p; p += (bytes + 255) & ~(size_t)255; return r; };
    float* X    = (float*)alloc((size_t)NTOK * D_ * 4);
    float* Rb   = (float*)alloc((size_t)NTOK * D_ * 4);
    bf16*  Xb   = (bf16*)alloc((size_t)NTOK * D_ * 2);
    bf16*  EMBb = (bf16*)alloc((size_t)NTOK * GDP_ * 2);
    bf16*  Hb   = (bf16*)alloc((size_t)NTOK * FFH_ * 2);
    bf16*  QKVb = (bf16*)alloc((size_t)NTOK * 3072 * 2);
    bf16*  qkvT = (bf16*)alloc((size_t)NB_ * 3072 * D_ * 2);
    bf16*  f1T  = (bf16*)alloc((size_t)NB_ * D_ * FFH_ * 2);
    bf16*  f2T  = (bf16*)alloc((size_t)NB_ * D_ * FFH_ * 2);
    bf16*  m1T  = (bf16*)alloc((size_t)MLPH_ * GDP_ * 2);
    bf16*  m2T  = (bf16*)alloc((size_t)D_ * MLPH_ * 2);
    float* bqkv = (float*)alloc((size_t)NB_ * 3072 * 4);
    bf16*  gB   = (bf16*)alloc((size_t)NTOK * T_ * 2);
    float* Pk   = (float*)alloc((size_t)4 * NTOK * D_ * 4);   // split-K partials

    // ---- prep: weights, biases, graph bias, embedding ----
    convT_kernel<<<dim3(D_ / 32, D_ / 32, NB_), 256, 0, stream>>>(
        wq, qkvT + 0, D_, D_, D_, (size_t)D_ * D_, (size_t)3072 * D_);
    convT_kernel<<<dim3(D_ / 32, D_ / 32, NB_), 256, 0, stream>>>(
        wk, qkvT + (size_t)1024 * D_, D_, D_, D_, (size_t)D_ * D_, (size_t)3072 * D_);
    convT_kernel<<<dim3(D_ / 32, D_ / 32, NB_), 256, 0, stream>>>(
        wv, qkvT + (size_t)2048 * D_, D_, D_, D_, (size_t)D_ * D_, (size_t)3072 * D_);
    convT_kernel<<<dim3(FFH_ / 32, D_ / 32, NB_), 256, 0, stream>>>(
        ffw1, f1T, D_, FFH_, D_, (size_t)D_ * FFH_, (size_t)D_ * FFH_);
    convT_kernel<<<dim3(D_ / 32, FFH_ / 32, NB_), 256, 0, stream>>>(
        ffw2, f2T, FFH_, D_, FFH_, (size_t)D_ * FFH_, (size_t)D_ * FFH_);
    convT_kernel<<<dim3(MLPH_ / 32, GDP_ / 32, 1), 256, 0, stream>>>(
        mlp_w1, m1T, GD_, MLPH_, GDP_, 0, 0);
    convT_kernel<<<dim3(D_ / 32, MLPH_ / 32, 1), 256, 0, stream>>>(
        mlp_w2, m2T, MLPH_, D_, MLPH_, 0, 0);
    bcat_kernel<<<dim3(NB_, 12), 256, 0, stream>>>(bq, bk, bv, bqkv);
    gbias_kernel<<<NTOK, 256, 0, stream>>>(syb_mask, syb_graph, gB);
    gather_kernel<<<NTOK, 256, 0, stream>>>(syb_ipt, emb, EMBb);

    // ---- MLP ----
    mm_bf16<true, false, false, false, false, bf16><<<dim3(MLPH_ / 128, NTOK / 128), 256, 0, stream>>>(
        EMBb, m1T, mlp_b1, nullptr, Hb, nullptr, NTOK, MLPH_, GDP_, GDP_);
    // MLP2 split-K: K=2048 -> 4 slices of 512, grid 8x32x4 = 1024 blocks
    mm_bf16<false, false, false, false, true, float><<<dim3(D_ / 128, NTOK / 128, 4), 256, 0, stream>>>(
        Hb, m2T, nullptr, nullptr, Pk, nullptr, NTOK, D_, MLPH_ / 4, MLPH_);
    mlp_fin_kernel<4><<<NTOK, 256, 0, stream>>>(Pk, mlp_b2, pos, X, Xb);

    for (int i = 0; i < NB_; i++) {
        // fused QKV projection (relu, Q scaled by 1/8)
        mm_bf16<true, false, false, true, false, bf16><<<dim3(3072 / 128, NTOK / 128), 256, 0, stream>>>(
            Xb, qkvT + (size_t)i * 3072 * D_, bqkv + (size_t)i * 3072, nullptr,
            QKVb, nullptr, NTOK, 3072, D_, D_);

        attn2_kernel<<<B_ * H_ * 4, 256, 0, stream>>>(QKVb, gB, syb_mask, Rb);

        add_ln_kernel<<<NTOK, 256, 0, stream>>>(
            X, Rb, ln1g + (size_t)i * D_, ln1b + (size_t)i * D_, X, Xb);

        mm_bf16<true, false, false, false, false, bf16><<<dim3(FFH_ / 128, NTOK / 128), 256, 0, stream>>>(
            Xb, f1T + (size_t)i * D_ * FFH_, ffb1 + (size_t)i * FFH_, nullptr, Hb, nullptr, NTOK, FFH_, D_, D_);

        // FF2 split-K: K=4096 -> 4 slices of 1024, grid 8x32x4 = 1024 blocks
        mm_bf16<false, false, false, false, true, float><<<dim3(D_ / 128, NTOK / 128, 4), 256, 0, stream>>>(
            Hb, f2T + (size_t)i * D_ * FFH_, nullptr, nullptr, Pk, nullptr, NTOK, D_, FFH_ / 4, FFH_);

        float* out_ptr = (i == NB_ - 1) ? (float*)d_out : X;
        add_ln_red_kernel<4><<<NTOK, 256, 0, stream>>>(
            X, Pk, ffb2 + (size_t)i * D_, ln2g + (size_t)i * D_, ln2b + (size_t)i * D_, out_ptr, Xb);
    }
}